// Round 6
// baseline (314.604 us; speedup 1.0000x reference)
//
#include <hip/hip_runtime.h>

// LinearAttention (fp32 in/out, bf16 internal MFMA):
// x(8,64,64,256) f32, w_qkv(256,1536) f32, gn_scale/bias(512) f32,
// w_out(512,256) f32, b_out(256) f32 -> out(8,64,64,256) f32
// B=8, N=4096 tokens/batch, HEADS=8, DH=64, HID=512, DIM=256.
//
// Softmaxes WITHOUT max subtraction (|q|,|k| <~ 6, exp fp32-safe).
// QKV GEMM split: q[token][512] token-major; k,v produced TRANSPOSED as
// kvT[feature][32768 tokens] (operand-swapped GEMM). exp(k) + ksum are
// computed in the kv-GEMM epilogue, so ctx is a pure bf16 MFMA GEMM.
// q-norm folded: MFMA on raw exp(q); epilogue row-scale by 0.125/s_n.
// GN folded into final GEMM: out = rs*(oa @ (gs.*w_out)) - rs*mu*gw1 + bias2

typedef unsigned short ushort_t;
typedef __attribute__((ext_vector_type(8))) short short8;
typedef __attribute__((ext_vector_type(4))) float floatx4;

__device__ __forceinline__ float b2f(ushort_t u) {
  unsigned int i = ((unsigned int)u) << 16;
  float f;
  __builtin_memcpy(&f, &i, 4);
  return f;
}
__device__ __forceinline__ ushort_t f2b(float f) {
  unsigned int i;
  __builtin_memcpy(&i, &f, 4);
  unsigned int r = (i + 0x7FFFu + ((i >> 16) & 1u)) >> 16;
  return (ushort_t)r;
}

// async 16B global->LDS copy (HW dest = wave-uniform base + lane*16)
__device__ __forceinline__ void load_lds16(const ushort_t* g, ushort_t* l) {
  __builtin_amdgcn_global_load_lds(
      (const __attribute__((address_space(1))) unsigned int*)g,
      (__attribute__((address_space(3))) unsigned int*)l, 16, 0, 0);
}

// ---------------------------------------------------------------------------
// Cast fp32 -> bf16, contiguous. 4 elements/thread.
// ---------------------------------------------------------------------------
__global__ __launch_bounds__(256) void cast_f32_bf16(
    const float* __restrict__ in, ushort_t* __restrict__ out) {
  long i = ((long)blockIdx.x * 256 + threadIdx.x) * 4;
  float4 v = *(const float4*)(in + i);
  ushort4 o;
  o.x = f2b(v.x);
  o.y = f2b(v.y);
  o.z = f2b(v.z);
  o.w = f2b(v.w);
  *(ushort4*)(out + i) = o;
}

// ---------------------------------------------------------------------------
// Transpose fp32 R x C -> bf16 C x R, optional per-row scale[r]. R,C mult 32.
// ---------------------------------------------------------------------------
__global__ __launch_bounds__(256) void transpose_f32_bf16(
    const float* __restrict__ in, ushort_t* __restrict__ out, int R, int C,
    const float* __restrict__ scale) {
  __shared__ ushort_t t[32][33];
  int c0 = blockIdx.x * 32, r0 = blockIdx.y * 32;
  int tx = threadIdx.x & 31, ty = threadIdx.x >> 5;  // ty 0..7
  for (int i = 0; i < 32; i += 8) {
    float s = scale ? scale[r0 + ty + i] : 1.0f;
    t[ty + i][tx] = f2b(in[(long)(r0 + ty + i) * C + c0 + tx] * s);
  }
  __syncthreads();
  for (int i = 0; i < 32; i += 8)
    out[(long)(c0 + ty + i) * R + r0 + tx] = t[tx][ty + i];
}

// ---------------------------------------------------------------------------
// Precompute gw1[c] = sum_f gs[f]*wout[f,c]; bias2[c] = sum gnb[f]*wout[f,c]
// + bout[c]. Grid 4 x 64 threads.
// ---------------------------------------------------------------------------
__global__ __launch_bounds__(64) void prep_gw_kernel(
    const float* __restrict__ gn_scale, const float* __restrict__ gn_bias,
    const float* __restrict__ w_out, const float* __restrict__ b_out,
    float* __restrict__ gw1, float* __restrict__ bias2) {
  int c = blockIdx.x * 64 + threadIdx.x;
  float g1 = 0.f, b2 = 0.f;
  for (int f = 0; f < 512; ++f) {
    float w = w_out[f * 256 + c];
    g1 += gn_scale[f] * w;
    b2 += gn_bias[f] * w;
  }
  gw1[c] = g1;
  bias2[c] = b2 + b_out[c];
}

// ---------------------------------------------------------------------------
// MFMA GEMM: C[M,F] = A[M,K] @ Bt[F,K]^T  (bf16 in, fp32 acc)
// MODE 0: bf16 out.
// MODE 1: bf16 out; rows < 512 (k-features) store exp(acc) and atomically
//         accumulate ksum[b*512 + row] (b = token-col >> 12).
// MODE 2: fp32 out with folded GroupNorm epilogue (murs, gw1, bias2).
// Block 256 = 4 waves 2x2; wave 64x64 via 4x4 mfma 16x16x32.
// ---------------------------------------------------------------------------
template <int MODE>
__global__ __launch_bounds__(256) void gemm_tpl(
    const ushort_t* __restrict__ A, const ushort_t* __restrict__ Bt,
    void* __restrict__ Cv, int M, int K, int F, float* __restrict__ ksum,
    const float* __restrict__ murs, const float* __restrict__ gw1,
    const float* __restrict__ bias2) {
  __shared__ __align__(16) ushort_t As[128][32];
  __shared__ __align__(16) ushort_t Bs[128][32];
  int tid = threadIdx.x;
  long m0 = (long)blockIdx.x * 128;
  long f0 = (long)blockIdx.y * 128;
  int wv = tid >> 6, lane = tid & 63;
  int wm = wv & 1, wf = wv >> 1;
  int l15 = lane & 15, quad = lane >> 4;

  floatx4 acc[4][4];
  floatx4 zero = {0.f, 0.f, 0.f, 0.f};
  for (int i = 0; i < 4; i++)
    for (int j = 0; j < 4; j++) acc[i][j] = zero;

  for (int k0 = 0; k0 < K; k0 += 32) {
    __syncthreads();
#pragma unroll
    for (int r = 0; r < 2; ++r) {
      int chunk = r * 256 + tid;  // 0..511
      int row = chunk >> 2;       // 0..127
      int kc = chunk & 3;         // 0..3 (8 bf16 each)
      load_lds16(A + (m0 + row) * (long)K + k0 + kc * 8, &As[row][kc * 8]);
      load_lds16(Bt + (f0 + row) * (long)K + k0 + kc * 8, &Bs[row][kc * 8]);
    }
    __syncthreads();
    short8 af[4], bfr[4];
#pragma unroll
    for (int mt = 0; mt < 4; mt++)
      af[mt] = *(const short8*)(&As[wm * 64 + mt * 16 + l15][quad * 8]);
#pragma unroll
    for (int ft = 0; ft < 4; ft++)
      bfr[ft] = *(const short8*)(&Bs[wf * 64 + ft * 16 + l15][quad * 8]);
#pragma unroll
    for (int mt = 0; mt < 4; mt++)
#pragma unroll
      for (int ft = 0; ft < 4; ft++)
        acc[mt][ft] = __builtin_amdgcn_mfma_f32_16x16x32_bf16(
            af[mt], bfr[ft], acc[mt][ft], 0, 0, 0);
  }

  // epilogue: D[row = quad*4 + r][col = l15] within each 16x16 tile
  if constexpr (MODE == 0) {
    ushort_t* C = (ushort_t*)Cv;
#pragma unroll
    for (int mt = 0; mt < 4; mt++)
#pragma unroll
      for (int ft = 0; ft < 4; ft++) {
        long col = f0 + wf * 64 + ft * 16 + l15;
#pragma unroll
        for (int r = 0; r < 4; r++) {
          long row = m0 + wm * 64 + mt * 16 + quad * 4 + r;
          C[row * F + col] = f2b(acc[mt][ft][r]);
        }
      }
  } else if constexpr (MODE == 1) {
    ushort_t* C = (ushort_t*)Cv;
    bool isk = (m0 < 512);
    float es[4][4] = {};
#pragma unroll
    for (int mt = 0; mt < 4; mt++)
#pragma unroll
      for (int ft = 0; ft < 4; ft++) {
        long col = f0 + wf * 64 + ft * 16 + l15;
#pragma unroll
        for (int r = 0; r < 4; r++) {
          long row = m0 + wm * 64 + mt * 16 + quad * 4 + r;
          float v = acc[mt][ft][r];
          if (isk) {
            v = __expf(v);
            es[mt][r] += v;
          }
          C[row * F + col] = f2b(v);
        }
      }
    if (isk) {
      int b = (int)(f0 >> 12);  // 4096 tokens per batch; 128-tile within one
#pragma unroll
      for (int mt = 0; mt < 4; mt++)
#pragma unroll
        for (int r = 0; r < 4; r++) {
          float s = es[mt][r];
          s += __shfl_xor(s, 1);
          s += __shfl_xor(s, 2);
          s += __shfl_xor(s, 4);
          s += __shfl_xor(s, 8);
          if (l15 == 0) {
            long row = m0 + wm * 64 + mt * 16 + quad * 4 + r;
            atomicAdd(&ksum[b * 512 + row], s);
          }
        }
    }
  } else {  // MODE 2: fp32 + folded GN
    float* C = (float*)Cv;
    int b = (int)(m0 >> 12);
    float mu = murs[b * 2], rs = murs[b * 2 + 1];
#pragma unroll
    for (int mt = 0; mt < 4; mt++)
#pragma unroll
      for (int ft = 0; ft < 4; ft++) {
        long col = f0 + wf * 64 + ft * 16 + l15;
        float c1 = bias2[col] - rs * mu * gw1[col];
#pragma unroll
        for (int r = 0; r < 4; r++) {
          long row = m0 + wm * 64 + mt * 16 + quad * 4 + r;
          C[row * F + col] = rs * acc[mt][ft][r] + c1;
        }
      }
  }
}

// ---------------------------------------------------------------------------
// ctxT[bh][e][d] += sum_n expk[d,n] * v[e,n]  via MFMA.
// kvT rows 0..511 = exp(k) features (from kv_gemm epilogue), 512..1023 = v.
// Grid (64 bh, 16 chunks of 256 n). Tiles 64x128, XOR-swizzled 16B chunks
// staged via global_load_lds. Wave w computes d-slice [w*16,w*16+16) x e 64.
// fp32 atomicAdd partials into zeroed ctxT.
// ---------------------------------------------------------------------------
__global__ __launch_bounds__(256) void ctx_mfma(
    const ushort_t* __restrict__ kvT, float* __restrict__ ctxT) {
  int bh = blockIdx.x, cy = blockIdx.y;
  int b = bh >> 3, h = bh & 7;
  int tid = threadIdx.x, wv = tid >> 6, lane = tid & 63;
  int l15 = lane & 15, quad = lane >> 4;
  __shared__ __align__(16) ushort_t kTs[64 * 128];
  __shared__ __align__(16) ushort_t vTs[64 * 128];
  const ushort_t* kbase = kvT + (long)(h * 64) * 32768 + b * 4096 + cy * 256;
  const ushort_t* vbase = kbase + (long)512 * 32768;

  floatx4 acc[4];
  floatx4 zero = {0.f, 0.f, 0.f, 0.f};
  for (int i = 0; i < 4; i++) acc[i] = zero;

  int r4 = lane >> 4, c = lane & 15;
  for (int tile = 0; tile < 2; ++tile) {
    __syncthreads();
#pragma unroll
    for (int i = 0; i < 4; ++i) {
      int row = wv * 16 + i * 4 + r4;
      int gc = (c & 8) | ((c ^ row) & 7);  // source chunk for dest slot c
      load_lds16(kbase + (long)row * 32768 + tile * 128 + gc * 8,
                 kTs + (wv * 16 + i * 4) * 128 + lane * 8);
      load_lds16(vbase + (long)row * 32768 + tile * 128 + gc * 8,
                 vTs + (wv * 16 + i * 4) * 128 + lane * 8);
    }
    __syncthreads();
#pragma unroll
    for (int ks = 0; ks < 4; ++ks) {
      int d = wv * 16 + l15;
      int cidx = ks * 4 + quad;
      int sa = (cidx & 8) | ((cidx ^ d) & 7);
      short8 a = *(const short8*)(kTs + d * 128 + sa * 8);
      short8 bf[4];
#pragma unroll
      for (int ft = 0; ft < 4; ++ft) {
        int e = ft * 16 + l15;
        int sb = (cidx & 8) | ((cidx ^ e) & 7);
        bf[ft] = *(const short8*)(vTs + e * 128 + sb * 8);
      }
#pragma unroll
      for (int ft = 0; ft < 4; ++ft)
        acc[ft] = __builtin_amdgcn_mfma_f32_16x16x32_bf16(a, bf[ft], acc[ft],
                                                          0, 0, 0);
    }
  }
  // D[row=d: quad*4+r][col=e: l15] per 16x16 tile -> ctxT[e][d]
  float* cb = ctxT + (long)bh * 4096;
#pragma unroll
  for (int ft = 0; ft < 4; ++ft)
#pragma unroll
    for (int r = 0; r < 4; ++r)
      atomicAdd(&cb[(ft * 16 + l15) * 64 + wv * 16 + quad * 4 + r],
                acc[ft][r]);
}

// ---------------------------------------------------------------------------
// Fused q-softmax + P@ctx MFMA, shuffle-free. Grid (64 bh, 16 chunks of 256).
// q-tile staged via global_load_lds into XOR-swizzled LDS; per-thread exp+sum
// (thread t owns token t); MFMA on raw exp; epilogue row-scales by 0.125/s_n.
// ctx scaled by 1/ksum[d] at staging. Writes A2 (bf16) + GN stats atomics.
// ---------------------------------------------------------------------------
__global__ __launch_bounds__(256) void qp_gemm_kernel(
    const ushort_t* __restrict__ q, const float* __restrict__ ctxT,
    const float* __restrict__ ksum, ushort_t* __restrict__ A2,
    float* __restrict__ gstats) {
  int bh = blockIdx.x, chunk = blockIdx.y;
  int b = bh >> 3, h = bh & 7;
  int tid = threadIdx.x, wv = tid >> 6, lane = tid & 63;
  int l15 = lane & 15, quad = lane >> 4;
  __shared__ __align__(16) ushort_t As[256 * 64];  // swizzled 128B rows
  __shared__ __align__(16) ushort_t Bs[64 * 64];   // swizzled 128B rows
  __shared__ float kv[64];
  __shared__ float rs[256];
  __shared__ float red[4][2];

  long rowbase = (long)b * 4096 + chunk * 256;

  // kinv -> LDS
  if (tid < 64) kv[tid] = 1.0f / ksum[bh * 64 + tid];

  // stage q-tile (256 tok x 64 d) via global_load_lds, swizzled chunks
  {
    int tl = lane >> 3;  // token-in-group 0..7
    int c = lane & 7;    // dest chunk slot
    int j = c ^ tl;      // source chunk (tok&7 == tl)
    const ushort_t* g = q + (rowbase + wv * 64 + tl) * 512 + h * 64 + j * 8;
#pragma unroll
    for (int i = 0; i < 8; ++i)
      load_lds16(g + (long)i * 8 * 512, As + (wv * 64 + i * 8) * 64 + lane * 8);
  }

  // read ctxT tile (64x64 f32) into regs while loads fly
  int be = tid >> 2, d0 = (tid & 3) * 16;
  float4 cv[4];
  {
    const float* src = ctxT + (long)bh * 4096 + be * 64 + d0;
#pragma unroll
    for (int j = 0; j < 4; ++j) cv[j] = *(const float4*)(src + j * 4);
  }
  __syncthreads();  // q-tile + kv visible

  // Bs[e][d] = bf16(ctxT[e][d] * kinv[d]), swizzled
  {
#pragma unroll
    for (int j2 = 0; j2 < 2; ++j2) {
      int chunkd = (d0 >> 3) + j2;
      int slot = chunkd ^ (be & 7);
      short8 o;
#pragma unroll
      for (int u = 0; u < 8; ++u) {
        float f = ((const float*)cv)[j2 * 8 + u] * kv[d0 + j2 * 8 + u];
        o[u] = (short)f2b(f);
      }
      *(short8*)(Bs + be * 64 + slot * 8) = o;
    }
  }

  // per-thread softmax-sum: thread t owns token t; exp in place, sum in reg
  {
    int t7 = tid & 7;
    ushort_t* row = As + tid * 64;
    float s = 0.f;
#pragma unroll
    for (int j = 0; j < 8; ++j) {
      int slot = j ^ t7;
      short8 vq = *(const short8*)(row + slot * 8);
      short8 eo;
#pragma unroll
      for (int u = 0; u < 8; ++u) {
        float e = __expf(b2f((ushort_t)vq[u]));
        s += e;
        eo[u] = (short)f2b(e);
      }
      *(short8*)(row + slot * 8) = eo;
    }
    rs[tid] = 0.125f / s;
  }
  __syncthreads();  // As(exp) + Bs + rs visible

  // MFMA: wave wv -> tokens wv*64..+63 x e 0..63 (4x4 of 16x16, K=64)
  floatx4 acc[4][4];
  floatx4 zero = {0.f, 0.f, 0.f, 0.f};
  for (int i = 0; i < 4; i++)
    for (int j = 0; j < 4; j++) acc[i][j] = zero;
#pragma unroll
  for (int k0 = 0; k0 < 2; ++k0) {
    short8 af[4], bfr[4];
#pragma unroll
    for (int mt = 0; mt < 4; mt++) {
      int row = wv * 64 + mt * 16 + l15;
      int slot = (k0 * 4 + quad) ^ (row & 7);
      af[mt] = *(const short8*)(As + row * 64 + slot * 8);
    }
#pragma unroll
    for (int ft = 0; ft < 4; ft++) {
      int e = ft * 16 + l15;
      int slot = (k0 * 4 + quad) ^ (e & 7);
      bfr[ft] = *(const short8*)(Bs + e * 64 + slot * 8);
    }
#pragma unroll
    for (int mt = 0; mt < 4; mt++)
#pragma unroll
      for (int ft = 0; ft < 4; ft++)
        acc[mt][ft] = __builtin_amdgcn_mfma_f32_16x16x32_bf16(
            af[mt], bfr[ft], acc[mt][ft], 0, 0, 0);
  }

  // epilogue: row-scale by rs, bf16 store, GN stats
  float lsum = 0.f, lss = 0.f;
#pragma unroll
  for (int mt = 0; mt < 4; mt++) {
    float rsv[4];
#pragma unroll
    for (int r = 0; r < 4; r++)
      rsv[r] = rs[wv * 64 + mt * 16 + quad * 4 + r];
#pragma unroll
    for (int ft = 0; ft < 4; ft++) {
      int col = h * 64 + ft * 16 + l15;
#pragma unroll
      for (int r = 0; r < 4; r++) {
        long row = rowbase + wv * 64 + mt * 16 + quad * 4 + r;
        float v = acc[mt][ft][r] * rsv[r];
        A2[row * 512 + col] = f2b(v);
        lsum += v;
        lss += v * v;
      }
    }
  }
  for (int o = 32; o > 0; o >>= 1) {
    lsum += __shfl_xor(lsum, o);
    lss += __shfl_xor(lss, o);
  }
  if (lane == 0) {
    red[wv][0] = lsum;
    red[wv][1] = lss;
  }
  __syncthreads();
  if (tid == 0) {
    float a = 0.f, c = 0.f;
    for (int w2 = 0; w2 < 4; w2++) {
      a += red[w2][0];
      c += red[w2][1];
    }
    atomicAdd(&gstats[b * 2], a);
    atomicAdd(&gstats[b * 2 + 1], c);
  }
}

// ---------------------------------------------------------------------------
// mu/rsqrt per batch from gstats. 1 block, 64 threads.
// ---------------------------------------------------------------------------
__global__ __launch_bounds__(64) void finalize_murs(
    const float* __restrict__ gstats, float* __restrict__ murs) {
  int tid = threadIdx.x;
  if (tid < 8) {
    float cnt = 4096.f * 512.f;
    float mu = gstats[tid * 2] / cnt;
    float var = gstats[tid * 2 + 1] / cnt - mu * mu;
    murs[tid * 2] = mu;
    murs[tid * 2 + 1] = rsqrtf(var + 1e-5f);
  }
}

// ---------------------------------------------------------------------------
extern "C" void kernel_launch(void* const* d_in, const int* in_sizes, int n_in,
                              void* d_out, int out_size, void* d_ws,
                              size_t ws_size, hipStream_t stream) {
  const float* x = (const float*)d_in[0];         // 8*64*64*256 f32
  const float* w_qkv = (const float*)d_in[1];     // 256*1536 f32
  const float* gn_scale = (const float*)d_in[2];  // 512 f32
  const float* gn_bias = (const float*)d_in[3];   // 512 f32
  const float* w_out = (const float*)d_in[4];     // 512*256 f32
  const float* b_out = (const float*)d_in[5];     // 256 f32
  float* out = (float*)d_out;                     // 8*64*64*256 f32

  char* w = (char*)d_ws;
  ushort_t* q = (ushort_t*)(w + 0);              // 33554432 B (32768x512 bf16)
  ushort_t* kvT = (ushort_t*)(w + 33554432);     // 67108864 B (1024x32768 bf16)
  ushort_t* A2 = (ushort_t*)(w + 100663296);     // 33554432 B (32768x512 bf16)
  ushort_t* xb = (ushort_t*)(w + 167772160);     // 16777216 B (32768x256 bf16)
  ushort_t* wqkvT = (ushort_t*)(w + 184549376);  // 786432 B (1536x256 bf16)
  ushort_t* w2T = (ushort_t*)(w + 185335808);    // 262144 B (256x512 bf16)
  float* ctxT = (float*)(w + 185630720);         // 1048576 B (64*64*64 f32)
  float* gstats = (float*)(w + 186679296);       // 64 B (8 x {sum,ss})
  float* ksum = (float*)(w + 186679360);         // 16384 B (8*512 f32)
  float* murs = (float*)(w + 186695744);         // 64 B
  float* bias2 = (float*)(w + 186695808);        // 1024 B
  float* gw1 = (float*)(w + 186696832);          // 1024 B

  // zero ctxT + gstats + ksum (contiguous)
  hipMemsetAsync(ctxT, 0, 1048576 + 64 + 16384, stream);

  // cast x -> bf16
  cast_f32_bf16<<<8388608 / 4 / 256, 256, 0, stream>>>(x, xb);
  // transposes+cast: w_qkv -> (1536x256); w_out -> gs-scaled (256x512)
  transpose_f32_bf16<<<dim3(1536 / 32, 256 / 32), 256, 0, stream>>>(
      w_qkv, wqkvT, 256, 1536, nullptr);
  transpose_f32_bf16<<<dim3(256 / 32, 512 / 32), 256, 0, stream>>>(
      w_out, w2T, 512, 256, gn_scale);
  // gw1 + bias2 precompute
  prep_gw_kernel<<<4, 64, 0, stream>>>(gn_scale, gn_bias, w_out, b_out, gw1,
                                       bias2);
  // q GEMM: (32768x256)@(256x512) -> q[token][512] bf16
  gemm_tpl<0><<<dim3(256, 4), 256, 0, stream>>>(
      xb, wqkvT, q, 32768, 256, 512, nullptr, nullptr, nullptr, nullptr);
  // kv GEMM transposed: (1024x256)@(256x32768) -> kvT[feat][token] bf16,
  // with exp(k) + ksum in epilogue
  gemm_tpl<1><<<dim3(8, 256), 256, 0, stream>>>(
      wqkvT + 512 * 256, xb, kvT, 1024, 256, 32768, ksum, nullptr, nullptr,
      nullptr);
  // context: pure MFMA over n
  ctx_mfma<<<dim3(64, 16), 256, 0, stream>>>(kvT, ctxT);
  // fused q-softmax + P@ctx -> A2 (bf16) + GN stats
  qp_gemm_kernel<<<dim3(64, 16), 256, 0, stream>>>(q, ctxT, ksum, A2, gstats);
  // mu / rsqrt per batch
  finalize_murs<<<1, 64, 0, stream>>>(gstats, murs);
  // final GEMM with folded GN epilogue: (32768x512)@(512x256) -> fp32 out
  gemm_tpl<2><<<dim3(256, 2), 256, 0, stream>>>(
      A2, w2T, out, 32768, 512, 256, nullptr, murs, gw1, bias2);
}

// Round 7
// 255.850 us; speedup vs baseline: 1.2296x; 1.2296x over previous
//
#include <hip/hip_runtime.h>

// LinearAttention (fp32 in/out, bf16 internal MFMA):
// x(8,64,64,256) f32, w_qkv(256,1536) f32, gn_scale/bias(512) f32,
// w_out(512,256) f32, b_out(256) f32 -> out(8,64,64,256) f32
// B=8, N=4096 tokens/batch, HEADS=8, DH=64, HID=512, DIM=256.
//
// Softmaxes WITHOUT max subtraction (|q|,|k| <~ 6, exp fp32-safe).
// QKV GEMM split: q[token][512] token-major; k,v produced TRANSPOSED as
// kvT[feature][32768 tokens] (operand-swapped GEMM), k rows store exp().
// ctx is a pure bf16 MFMA GEMM writing NON-ATOMIC per-chunk partials;
// ksum partials come from an extra MFMA vs an all-ones B fragment.
// reduce_kernel folds partials -> ctxT + ksum (no atomics anywhere hot).
// q-norm folded: MFMA on raw exp(q); epilogue row-scale by 0.125/s_n.
// GN folded into final GEMM: out = rs*(oa @ (gs.*w_out)) - rs*mu*gw1 + bias2

typedef unsigned short ushort_t;
typedef __attribute__((ext_vector_type(8))) short short8;
typedef __attribute__((ext_vector_type(4))) float floatx4;

__device__ __forceinline__ float b2f(ushort_t u) {
  unsigned int i = ((unsigned int)u) << 16;
  float f;
  __builtin_memcpy(&f, &i, 4);
  return f;
}
__device__ __forceinline__ ushort_t f2b(float f) {
  unsigned int i;
  __builtin_memcpy(&i, &f, 4);
  unsigned int r = (i + 0x7FFFu + ((i >> 16) & 1u)) >> 16;
  return (ushort_t)r;
}

// async 16B global->LDS copy (HW dest = wave-uniform base + lane*16)
__device__ __forceinline__ void load_lds16(const ushort_t* g, ushort_t* l) {
  __builtin_amdgcn_global_load_lds(
      (const __attribute__((address_space(1))) unsigned int*)g,
      (__attribute__((address_space(3))) unsigned int*)l, 16, 0, 0);
}

// ---------------------------------------------------------------------------
// Cast fp32 -> bf16, contiguous. 4 elements/thread.
// ---------------------------------------------------------------------------
__global__ __launch_bounds__(256) void cast_f32_bf16(
    const float* __restrict__ in, ushort_t* __restrict__ out) {
  long i = ((long)blockIdx.x * 256 + threadIdx.x) * 4;
  float4 v = *(const float4*)(in + i);
  ushort4 o;
  o.x = f2b(v.x);
  o.y = f2b(v.y);
  o.z = f2b(v.z);
  o.w = f2b(v.w);
  *(ushort4*)(out + i) = o;
}

// ---------------------------------------------------------------------------
// Transpose fp32 R x C -> bf16 C x R, optional per-row scale[r]. R,C mult 32.
// ---------------------------------------------------------------------------
__global__ __launch_bounds__(256) void transpose_f32_bf16(
    const float* __restrict__ in, ushort_t* __restrict__ out, int R, int C,
    const float* __restrict__ scale) {
  __shared__ ushort_t t[32][33];
  int c0 = blockIdx.x * 32, r0 = blockIdx.y * 32;
  int tx = threadIdx.x & 31, ty = threadIdx.x >> 5;  // ty 0..7
  for (int i = 0; i < 32; i += 8) {
    float s = scale ? scale[r0 + ty + i] : 1.0f;
    t[ty + i][tx] = f2b(in[(long)(r0 + ty + i) * C + c0 + tx] * s);
  }
  __syncthreads();
  for (int i = 0; i < 32; i += 8)
    out[(long)(c0 + ty + i) * R + r0 + tx] = t[tx][ty + i];
}

// ---------------------------------------------------------------------------
// Precompute gw1[c] = sum_f gs[f]*wout[f,c]; bias2[c] = sum gnb[f]*wout[f,c]
// + bout[c]. Grid 4 x 64 threads.
// ---------------------------------------------------------------------------
__global__ __launch_bounds__(64) void prep_gw_kernel(
    const float* __restrict__ gn_scale, const float* __restrict__ gn_bias,
    const float* __restrict__ w_out, const float* __restrict__ b_out,
    float* __restrict__ gw1, float* __restrict__ bias2) {
  int c = blockIdx.x * 64 + threadIdx.x;
  float g1 = 0.f, b2 = 0.f;
  for (int f = 0; f < 512; ++f) {
    float w = w_out[f * 256 + c];
    g1 += gn_scale[f] * w;
    b2 += gn_bias[f] * w;
  }
  gw1[c] = g1;
  bias2[c] = b2 + b_out[c];
}

// ---------------------------------------------------------------------------
// MFMA GEMM: C[M,F] = A[M,K] @ Bt[F,K]^T  (bf16 in, fp32 acc)
// MODE 0: bf16 out.
// MODE 1: bf16 out; rows < 512 (k-features) store exp(acc).
// MODE 2: fp32 out with folded GroupNorm epilogue (murs, gw1, bias2).
// Block 256 = 4 waves 2x2; wave 64x64 via 4x4 mfma 16x16x32.
// ---------------------------------------------------------------------------
template <int MODE>
__global__ __launch_bounds__(256) void gemm_tpl(
    const ushort_t* __restrict__ A, const ushort_t* __restrict__ Bt,
    void* __restrict__ Cv, int M, int K, int F,
    const float* __restrict__ murs, const float* __restrict__ gw1,
    const float* __restrict__ bias2) {
  __shared__ __align__(16) ushort_t As[128][32];
  __shared__ __align__(16) ushort_t Bs[128][32];
  int tid = threadIdx.x;
  long m0 = (long)blockIdx.x * 128;
  long f0 = (long)blockIdx.y * 128;
  int wv = tid >> 6, lane = tid & 63;
  int wm = wv & 1, wf = wv >> 1;
  int l15 = lane & 15, quad = lane >> 4;

  floatx4 acc[4][4];
  floatx4 zero = {0.f, 0.f, 0.f, 0.f};
  for (int i = 0; i < 4; i++)
    for (int j = 0; j < 4; j++) acc[i][j] = zero;

  for (int k0 = 0; k0 < K; k0 += 32) {
    __syncthreads();
#pragma unroll
    for (int r = 0; r < 2; ++r) {
      int chunk = r * 256 + tid;  // 0..511
      int row = chunk >> 2;       // 0..127
      int kc = chunk & 3;         // 0..3 (8 bf16 each)
      load_lds16(A + (m0 + row) * (long)K + k0 + kc * 8, &As[row][kc * 8]);
      load_lds16(Bt + (f0 + row) * (long)K + k0 + kc * 8, &Bs[row][kc * 8]);
    }
    __syncthreads();
    short8 af[4], bfr[4];
#pragma unroll
    for (int mt = 0; mt < 4; mt++)
      af[mt] = *(const short8*)(&As[wm * 64 + mt * 16 + l15][quad * 8]);
#pragma unroll
    for (int ft = 0; ft < 4; ft++)
      bfr[ft] = *(const short8*)(&Bs[wf * 64 + ft * 16 + l15][quad * 8]);
#pragma unroll
    for (int mt = 0; mt < 4; mt++)
#pragma unroll
      for (int ft = 0; ft < 4; ft++)
        acc[mt][ft] = __builtin_amdgcn_mfma_f32_16x16x32_bf16(
            af[mt], bfr[ft], acc[mt][ft], 0, 0, 0);
  }

  // epilogue: D[row = quad*4 + r][col = l15] within each 16x16 tile
  if constexpr (MODE == 0) {
    ushort_t* C = (ushort_t*)Cv;
#pragma unroll
    for (int mt = 0; mt < 4; mt++)
#pragma unroll
      for (int ft = 0; ft < 4; ft++) {
        long col = f0 + wf * 64 + ft * 16 + l15;
#pragma unroll
        for (int r = 0; r < 4; r++) {
          long row = m0 + wm * 64 + mt * 16 + quad * 4 + r;
          C[row * F + col] = f2b(acc[mt][ft][r]);
        }
      }
  } else if constexpr (MODE == 1) {
    ushort_t* C = (ushort_t*)Cv;
    bool isk = (m0 < 512);
#pragma unroll
    for (int mt = 0; mt < 4; mt++)
#pragma unroll
      for (int ft = 0; ft < 4; ft++) {
        long col = f0 + wf * 64 + ft * 16 + l15;
#pragma unroll
        for (int r = 0; r < 4; r++) {
          long row = m0 + wm * 64 + mt * 16 + quad * 4 + r;
          float v = acc[mt][ft][r];
          if (isk) v = __expf(v);
          C[row * F + col] = f2b(v);
        }
      }
  } else {  // MODE 2: fp32 + folded GN
    float* C = (float*)Cv;
    int b = (int)(m0 >> 12);
    float mu = murs[b * 2], rs = murs[b * 2 + 1];
#pragma unroll
    for (int mt = 0; mt < 4; mt++)
#pragma unroll
      for (int ft = 0; ft < 4; ft++) {
        long col = f0 + wf * 64 + ft * 16 + l15;
        float c1 = bias2[col] - rs * mu * gw1[col];
#pragma unroll
        for (int r = 0; r < 4; r++) {
          long row = m0 + wm * 64 + mt * 16 + quad * 4 + r;
          C[row * F + col] = rs * acc[mt][ft][r] + c1;
        }
      }
  }
}

// ---------------------------------------------------------------------------
// ctx partials via MFMA. kvT rows 0..511 = exp(k), 512..1023 = v.
// Grid (64 bh, 16 chunks of 256 n). Per chunk, NON-ATOMIC partial write:
//   ctxP[(cy*64+bh)*4096 + e*64 + d] = sum_n expk[d,n]*v[e,n]
//   ksumP[(cy*64+bh)*64 + d]         = sum_n expk[d,n]   (ones-MFMA)
// Wave w owns d-slice [w*16, w*16+16).
// ---------------------------------------------------------------------------
__global__ __launch_bounds__(256) void ctx_mfma(
    const ushort_t* __restrict__ kvT, float* __restrict__ ctxP,
    float* __restrict__ ksumP) {
  int bh = blockIdx.x, cy = blockIdx.y;
  int b = bh >> 3, h = bh & 7;
  int tid = threadIdx.x, wv = tid >> 6, lane = tid & 63;
  int l15 = lane & 15, quad = lane >> 4;
  __shared__ __align__(16) ushort_t kTs[64 * 128];
  __shared__ __align__(16) ushort_t vTs[64 * 128];
  const ushort_t* kbase = kvT + (long)(h * 64) * 32768 + b * 4096 + cy * 256;
  const ushort_t* vbase = kbase + (long)512 * 32768;

  floatx4 acc[4], acc1;
  floatx4 zero = {0.f, 0.f, 0.f, 0.f};
  for (int i = 0; i < 4; i++) acc[i] = zero;
  acc1 = zero;
  short8 ones;
#pragma unroll
  for (int u = 0; u < 8; ++u) ones[u] = (short)0x3F80;  // bf16 1.0

  int r4 = lane >> 4, c = lane & 15;
  for (int tile = 0; tile < 2; ++tile) {
    __syncthreads();
#pragma unroll
    for (int i = 0; i < 4; ++i) {
      int row = wv * 16 + i * 4 + r4;
      int gc = (c & 8) | ((c ^ row) & 7);  // source chunk for dest slot c
      load_lds16(kbase + (long)row * 32768 + tile * 128 + gc * 8,
                 kTs + (wv * 16 + i * 4) * 128 + lane * 8);
      load_lds16(vbase + (long)row * 32768 + tile * 128 + gc * 8,
                 vTs + (wv * 16 + i * 4) * 128 + lane * 8);
    }
    __syncthreads();
#pragma unroll
    for (int ks = 0; ks < 4; ++ks) {
      int d = wv * 16 + l15;
      int cidx = ks * 4 + quad;
      int sa = (cidx & 8) | ((cidx ^ d) & 7);
      short8 a = *(const short8*)(kTs + d * 128 + sa * 8);
      short8 bf[4];
#pragma unroll
      for (int ft = 0; ft < 4; ++ft) {
        int e = ft * 16 + l15;
        int sb = (cidx & 8) | ((cidx ^ e) & 7);
        bf[ft] = *(const short8*)(vTs + e * 128 + sb * 8);
      }
#pragma unroll
      for (int ft = 0; ft < 4; ++ft)
        acc[ft] = __builtin_amdgcn_mfma_f32_16x16x32_bf16(a, bf[ft], acc[ft],
                                                          0, 0, 0);
      acc1 = __builtin_amdgcn_mfma_f32_16x16x32_bf16(a, ones, acc1, 0, 0, 0);
    }
  }
  // D[row=d: quad*4+r][col=e: l15] per 16x16 tile -> ctxP[e][d] (partial)
  float* cb = ctxP + ((long)cy * 64 + bh) * 4096;
#pragma unroll
  for (int ft = 0; ft < 4; ++ft)
#pragma unroll
    for (int r = 0; r < 4; ++r)
      cb[(ft * 16 + l15) * 64 + wv * 16 + quad * 4 + r] = acc[ft][r];
  if (l15 == 0) {
    float* kb = ksumP + ((long)cy * 64 + bh) * 64;
#pragma unroll
    for (int r = 0; r < 4; ++r) kb[wv * 16 + quad * 4 + r] = acc1[r];
  }
}

// ---------------------------------------------------------------------------
// Reduce 16 chunk-partials: ctxT[bh*4096+j] = sum_c ctxP[(c*64+bh)*4096+j];
// ksum[bh*64+d] = sum_c ksumP[(c*64+bh)*64+d].
// Grid 1040 x 256: blocks 0..1023 -> ctx (262144 elems), 1024..1039 -> ksum.
// ---------------------------------------------------------------------------
__global__ __launch_bounds__(256) void reduce_kernel(
    const float* __restrict__ ctxP, const float* __restrict__ ksumP,
    float* __restrict__ ctxT, float* __restrict__ ksum) {
  int bid = blockIdx.x;
  if (bid < 1024) {
    int t = bid * 256 + threadIdx.x;  // 0..262143
    int bh = t >> 12, j = t & 4095;
    float s = 0.f;
#pragma unroll
    for (int c = 0; c < 16; ++c) s += ctxP[((long)c * 64 + bh) * 4096 + j];
    ctxT[t] = s;
  } else {
    int t = (bid - 1024) * 256 + threadIdx.x;  // 0..4095
    int bh = t >> 6, d = t & 63;
    float s = 0.f;
#pragma unroll
    for (int c = 0; c < 16; ++c) s += ksumP[((long)c * 64 + bh) * 64 + d];
    ksum[t] = s;
  }
}

// ---------------------------------------------------------------------------
// Fused q-softmax + P@ctx MFMA, shuffle-free. Grid (64 bh, 16 chunks of 256).
// q-tile staged via global_load_lds into XOR-swizzled LDS; per-thread exp+sum
// (thread t owns token t); MFMA on raw exp; epilogue row-scales by 0.125/s_n.
// ctx scaled by 1/ksum[d] at staging. Writes A2 (bf16) + GN stats atomics.
// ---------------------------------------------------------------------------
__global__ __launch_bounds__(256) void qp_gemm_kernel(
    const ushort_t* __restrict__ q, const float* __restrict__ ctxT,
    const float* __restrict__ ksum, ushort_t* __restrict__ A2,
    float* __restrict__ gstats) {
  int bh = blockIdx.x, chunk = blockIdx.y;
  int b = bh >> 3, h = bh & 7;
  int tid = threadIdx.x, wv = tid >> 6, lane = tid & 63;
  int l15 = lane & 15, quad = lane >> 4;
  __shared__ __align__(16) ushort_t As[256 * 64];  // swizzled 128B rows
  __shared__ __align__(16) ushort_t Bs[64 * 64];   // swizzled 128B rows
  __shared__ float kv[64];
  __shared__ float rs[256];
  __shared__ float red[4][2];

  long rowbase = (long)b * 4096 + chunk * 256;

  // kinv -> LDS
  if (tid < 64) kv[tid] = 1.0f / ksum[bh * 64 + tid];

  // stage q-tile (256 tok x 64 d) via global_load_lds, swizzled chunks
  {
    int tl = lane >> 3;  // token-in-group 0..7
    int c = lane & 7;    // dest chunk slot
    int j = c ^ tl;      // source chunk (tok&7 == tl)
    const ushort_t* g = q + (rowbase + wv * 64 + tl) * 512 + h * 64 + j * 8;
#pragma unroll
    for (int i = 0; i < 8; ++i)
      load_lds16(g + (long)i * 8 * 512, As + (wv * 64 + i * 8) * 64 + lane * 8);
  }

  // read ctxT tile (64x64 f32) into regs while loads fly
  int be = tid >> 2, d0 = (tid & 3) * 16;
  float4 cv[4];
  {
    const float* src = ctxT + (long)bh * 4096 + be * 64 + d0;
#pragma unroll
    for (int j = 0; j < 4; ++j) cv[j] = *(const float4*)(src + j * 4);
  }
  __syncthreads();  // q-tile + kv visible

  // Bs[e][d] = bf16(ctxT[e][d] * kinv[d]), swizzled
  {
#pragma unroll
    for (int j2 = 0; j2 < 2; ++j2) {
      int chunkd = (d0 >> 3) + j2;
      int slot = chunkd ^ (be & 7);
      short8 o;
#pragma unroll
      for (int u = 0; u < 8; ++u) {
        float f = ((const float*)cv)[j2 * 8 + u] * kv[d0 + j2 * 8 + u];
        o[u] = (short)f2b(f);
      }
      *(short8*)(Bs + be * 64 + slot * 8) = o;
    }
  }

  // per-thread softmax-sum: thread t owns token t; exp in place, sum in reg
  {
    int t7 = tid & 7;
    ushort_t* row = As + tid * 64;
    float s = 0.f;
#pragma unroll
    for (int j = 0; j < 8; ++j) {
      int slot = j ^ t7;
      short8 vq = *(const short8*)(row + slot * 8);
      short8 eo;
#pragma unroll
      for (int u = 0; u < 8; ++u) {
        float e = __expf(b2f((ushort_t)vq[u]));
        s += e;
        eo[u] = (short)f2b(e);
      }
      *(short8*)(row + slot * 8) = eo;
    }
    rs[tid] = 0.125f / s;
  }
  __syncthreads();  // As(exp) + Bs + rs visible

  // MFMA: wave wv -> tokens wv*64..+63 x e 0..63 (4x4 of 16x16, K=64)
  floatx4 acc[4][4];
  floatx4 zero = {0.f, 0.f, 0.f, 0.f};
  for (int i = 0; i < 4; i++)
    for (int j = 0; j < 4; j++) acc[i][j] = zero;
#pragma unroll
  for (int k0 = 0; k0 < 2; ++k0) {
    short8 af[4], bfr[4];
#pragma unroll
    for (int mt = 0; mt < 4; mt++) {
      int row = wv * 64 + mt * 16 + l15;
      int slot = (k0 * 4 + quad) ^ (row & 7);
      af[mt] = *(const short8*)(As + row * 64 + slot * 8);
    }
#pragma unroll
    for (int ft = 0; ft < 4; ft++) {
      int e = ft * 16 + l15;
      int slot = (k0 * 4 + quad) ^ (e & 7);
      bfr[ft] = *(const short8*)(Bs + e * 64 + slot * 8);
    }
#pragma unroll
    for (int mt = 0; mt < 4; mt++)
#pragma unroll
      for (int ft = 0; ft < 4; ft++)
        acc[mt][ft] = __builtin_amdgcn_mfma_f32_16x16x32_bf16(
            af[mt], bfr[ft], acc[mt][ft], 0, 0, 0);
  }

  // epilogue: row-scale by rs, bf16 store, GN stats
  float lsum = 0.f, lss = 0.f;
#pragma unroll
  for (int mt = 0; mt < 4; mt++) {
    float rsv[4];
#pragma unroll
    for (int r = 0; r < 4; r++)
      rsv[r] = rs[wv * 64 + mt * 16 + quad * 4 + r];
#pragma unroll
    for (int ft = 0; ft < 4; ft++) {
      int col = h * 64 + ft * 16 + l15;
#pragma unroll
      for (int r = 0; r < 4; r++) {
        long row = rowbase + wv * 64 + mt * 16 + quad * 4 + r;
        float v = acc[mt][ft][r] * rsv[r];
        A2[row * 512 + col] = f2b(v);
        lsum += v;
        lss += v * v;
      }
    }
  }
  for (int o = 32; o > 0; o >>= 1) {
    lsum += __shfl_xor(lsum, o);
    lss += __shfl_xor(lss, o);
  }
  if (lane == 0) {
    red[wv][0] = lsum;
    red[wv][1] = lss;
  }
  __syncthreads();
  if (tid == 0) {
    float a = 0.f, c = 0.f;
    for (int w2 = 0; w2 < 4; w2++) {
      a += red[w2][0];
      c += red[w2][1];
    }
    atomicAdd(&gstats[b * 2], a);
    atomicAdd(&gstats[b * 2 + 1], c);
  }
}

// ---------------------------------------------------------------------------
// mu/rsqrt per batch from gstats. 1 block, 64 threads.
// ---------------------------------------------------------------------------
__global__ __launch_bounds__(64) void finalize_murs(
    const float* __restrict__ gstats, float* __restrict__ murs) {
  int tid = threadIdx.x;
  if (tid < 8) {
    float cnt = 4096.f * 512.f;
    float mu = gstats[tid * 2] / cnt;
    float var = gstats[tid * 2 + 1] / cnt - mu * mu;
    murs[tid * 2] = mu;
    murs[tid * 2 + 1] = rsqrtf(var + 1e-5f);
  }
}

// ---------------------------------------------------------------------------
extern "C" void kernel_launch(void* const* d_in, const int* in_sizes, int n_in,
                              void* d_out, int out_size, void* d_ws,
                              size_t ws_size, hipStream_t stream) {
  const float* x = (const float*)d_in[0];         // 8*64*64*256 f32
  const float* w_qkv = (const float*)d_in[1];     // 256*1536 f32
  const float* gn_scale = (const float*)d_in[2];  // 512 f32
  const float* gn_bias = (const float*)d_in[3];   // 512 f32
  const float* w_out = (const float*)d_in[4];     // 512*256 f32
  const float* b_out = (const float*)d_in[5];     // 256 f32
  float* out = (float*)d_out;                     // 8*64*64*256 f32

  char* w = (char*)d_ws;
  ushort_t* q = (ushort_t*)(w + 0);              // 33554432 B (32768x512 bf16)
  ushort_t* kvT = (ushort_t*)(w + 33554432);     // 67108864 B (1024x32768 bf16)
  ushort_t* A2 = (ushort_t*)(w + 100663296);     // 33554432 B (32768x512 bf16)
  float* ctxP = (float*)(w + 134217728);         // 16777216 B (16*64*4096 f32)
  float* ksumP = (float*)(w + 150994944);        // 262144 B (16*64*64 f32)
  ushort_t* xb = (ushort_t*)(w + 167772160);     // 16777216 B (32768x256 bf16)
  ushort_t* wqkvT = (ushort_t*)(w + 184549376);  // 786432 B (1536x256 bf16)
  ushort_t* w2T = (ushort_t*)(w + 185335808);    // 262144 B (256x512 bf16)
  float* ctxT = (float*)(w + 185630720);         // 1048576 B (64*64*64 f32)
  float* gstats = (float*)(w + 186679296);       // 64 B (8 x {sum,ss})
  float* ksum = (float*)(w + 186679360);         // 16384 B (8*512 f32)
  float* murs = (float*)(w + 186695744);         // 64 B
  float* bias2 = (float*)(w + 186695808);        // 1024 B
  float* gw1 = (float*)(w + 186696832);          // 1024 B

  // zero gstats only (all other buffers fully written before read)
  hipMemsetAsync(gstats, 0, 64, stream);

  // cast x -> bf16
  cast_f32_bf16<<<8388608 / 4 / 256, 256, 0, stream>>>(x, xb);
  // transposes+cast: w_qkv -> (1536x256); w_out -> gs-scaled (256x512)
  transpose_f32_bf16<<<dim3(1536 / 32, 256 / 32), 256, 0, stream>>>(
      w_qkv, wqkvT, 256, 1536, nullptr);
  transpose_f32_bf16<<<dim3(256 / 32, 512 / 32), 256, 0, stream>>>(
      w_out, w2T, 512, 256, gn_scale);
  // gw1 + bias2 precompute
  prep_gw_kernel<<<4, 64, 0, stream>>>(gn_scale, gn_bias, w_out, b_out, gw1,
                                       bias2);
  // q GEMM: (32768x256)@(256x512) -> q[token][512] bf16
  gemm_tpl<0><<<dim3(256, 4), 256, 0, stream>>>(
      xb, wqkvT, q, 32768, 256, 512, nullptr, nullptr, nullptr);
  // kv GEMM transposed: (1024x256)@(256x32768) -> kvT[feat][token] bf16,
  // k rows store exp(acc)
  gemm_tpl<1><<<dim3(8, 256), 256, 0, stream>>>(
      wqkvT + 512 * 256, xb, kvT, 1024, 256, 32768, nullptr, nullptr, nullptr);
  // context partials: pure MFMA over n (non-atomic) + ksum via ones-MFMA
  ctx_mfma<<<dim3(64, 16), 256, 0, stream>>>(kvT, ctxP, ksumP);
  // fold partials -> ctxT + ksum
  reduce_kernel<<<1040, 256, 0, stream>>>(ctxP, ksumP, ctxT, ksum);
  // fused q-softmax + P@ctx -> A2 (bf16) + GN stats
  qp_gemm_kernel<<<dim3(64, 16), 256, 0, stream>>>(q, ctxT, ksum, A2, gstats);
  // mu / rsqrt per batch
  finalize_murs<<<1, 64, 0, stream>>>(gstats, murs);
  // final GEMM with folded GN epilogue: (32768x512)@(512x256) -> fp32 out
  gemm_tpl<2><<<dim3(256, 2), 256, 0, stream>>>(
      A2, w2T, out, 32768, 512, 256, murs, gw1, bias2);
}